// Round 15
// baseline (280.264 us; speedup 1.0000x reference)
//
#include <hip/hip_runtime.h>

#define DEVI __device__ __forceinline__

static constexpr int BB=4, CC=128, LLn=4096, DI=256, NS=16, RR=8, SS=4;
static constexpr int PP = RR + 2*NS;            // 40
static constexpr int CT = 64, NCH = LLn/CT;     // scan chunking: 64 chunks of 64
static constexpr int NCHF = 64;                 // layout sizing unit (unchanged)
static constexpr size_t BLC  = (size_t)BB*LLn*CC;    // 2,097,152
static constexpr size_t BLD  = (size_t)BB*LLn*DI;    // 4,194,304
static constexpr size_t SBLD = (size_t)SS*BLD;
static constexpr size_t SBLP = (size_t)SS*BB*LLn*PP;

// ---- weight offsets inside ws (floats), padded to multiples of 4 ----
static constexpr int OW_LN1W=0, OW_LN1B=128, OW_LN2W=256, OW_LN2B=384, OW_LN3W=512, OW_LN3B=640,
 OW_SPW=768, OW_CAW1=820, OW_CAW2=4916, OW_DWW=9012, OW_DWB=10164, OW_IPW=10292,
 OW_IP1W=75828, OW_IP2W=108596, OW_CVW=141364, OW_CVB=145460, OW_XPW=146484,
 OW_DTW=187444, OW_DTB=195636, OW_ALOG=196660, OW_DSK=213044, OW_OUTW=214068;
static constexpr int NW_RAW = 246836;   // last tensor end
static constexpr int NW_END = 246848;   // padded

__constant__ int c_woff[22] = {OW_LN1W,OW_LN1B,OW_LN2W,OW_LN2B,OW_LN3W,OW_LN3B,OW_SPW,OW_CAW1,
 OW_CAW2,OW_DWW,OW_DWB,OW_IPW,OW_IP1W,OW_IP2W,OW_CVW,OW_CVB,OW_XPW,OW_DTW,OW_DTB,OW_ALOG,
 OW_DSK,OW_OUTW};
__constant__ int c_wsz[22]  = {128,128,128,128,128,128,50,4096,4096,1152,128,65536,32768,32768,
 4096,1024,40960,8192,1024,16384,1024,32768};

// ---- workspace layout (float offsets) — byte-identical to round 13 ----
static constexpr size_t O_XF   = NW_END;              // aliased: bf16 padded xproj weights (4x64x256 shorts)
static constexpr size_t O_E1   = O_XF + BLC;          // (unused)
static constexpr size_t O_E2   = O_E1 + BLC;          // (unused)
static constexpr size_t O_Z    = O_E2 + BLC;          // z from in-proj (f32)
static constexpr size_t O_U    = O_Z + BLD;           // aliased: u streams bf16 (SBLD shorts); later y bf16
static constexpr size_t O_UC   = O_U + SBLD;          // aliased: uc in bf16 (SBLD shorts)
static constexpr size_t O_PROJ = O_UC + SBLD;         // aliased: proj in bf16 (SBLP shorts)
static constexpr size_t O_SDT  = O_PROJ + SBLP;                  // bf16: S*B*NCH*DI shorts
static constexpr size_t O_H    = O_SDT + (size_t)SS*BB*NCHF*DI;  // bf16 H: S*B*NCH*DI*NS shorts; aliased:
  // bf16 XBF [0,BLC) shorts, E1BF [BLC,2BLC), E2BF [2BLC,3BLC)  (dead before scan writes H)
  // bf16 GBF [0,BLD) shorts (written after scan, H dead)
static constexpr size_t O_M    = O_H + (size_t)SS*BB*NCHF*DI*NS;
static constexpr size_t O_S    = O_M + 2*(size_t)BB*2*LLn;
static constexpr size_t O_GF   = O_S + 2*(size_t)BB*LLn;   // aliased: bf16 in-proj weights
static constexpr size_t O_PART = O_GF + BLC;               // aliased: bf16 out_w
static constexpr size_t O_SIG  = O_PART + 2*(size_t)BB*32*CC;
static constexpr size_t WS_END = O_SIG + (size_t)BB*CC;

typedef __attribute__((ext_vector_type(8))) short short8v;   // 8 bf16 (4 VGPR)
typedef __attribute__((ext_vector_type(4))) float f32x4;     // MFMA acc

// ---- helpers ----
DEVI float bfu2f(unsigned short s){ union{unsigned u; float f;} c; c.u = ((unsigned)s)<<16; return c.f; }
DEVI unsigned short f2bfu(float f){ union{float f; unsigned u;} c; c.f=f;
  unsigned r = c.u + 0x7FFFu + ((c.u>>16)&1u); return (unsigned short)(r>>16); }
DEVI float4 bf4(uint2 v){ return make_float4(bfu2f((unsigned short)(v.x&0xFFFFu)), bfu2f((unsigned short)(v.x>>16)),
                                             bfu2f((unsigned short)(v.y&0xFFFFu)), bfu2f((unsigned short)(v.y>>16))); }
DEVI uint2 pk4(float4 v){ uint2 p;
  p.x = (unsigned)f2bfu(v.x) | ((unsigned)f2bfu(v.y)<<16);
  p.y = (unsigned)f2bfu(v.z) | ((unsigned)f2bfu(v.w)<<16); return p; }
DEVI bool bfmode(const void* ln1w){ return *(const unsigned*)ln1w == 0x3F803F80u; }
DEVI float2 ldin2(const void* p, int i, bool isbf){
  if(isbf){ unsigned v = *(const unsigned*)((const unsigned short*)p + i);
    return make_float2(bfu2f((unsigned short)(v & 0xFFFFu)), bfu2f((unsigned short)(v >> 16))); }
  const float* f = (const float*)p + i; return make_float2(f[0], f[1]);
}
DEVI float wsum(float v){
#pragma unroll
  for(int o=32;o;o>>=1) v += __shfl_xor(v,o,64);
  return v; }
DEVI float wmaxr(float v){
#pragma unroll
  for(int o=32;o;o>>=1) v = fmaxf(v, __shfl_xor(v,o,64));
  return v; }
DEVI float sigf(float x){ return 1.f/(1.f+__expf(-x)); }
// layernorm over 128 channels held as 2 values/lane across one 64-lane wave
DEVI float2 ln_wave(float2 x, const float* Wf, int ow, int ob, int lane){
  float mu = wsum(x.x + x.y) * (1.f/(float)CC);
  float dx = x.x - mu, dy = x.y - mu;
  float var = wsum(dx*dx + dy*dy) * (1.f/(float)CC);
  float rs = rsqrtf(var + 1e-5f);
  int c = 2*lane;
  return make_float2(dx*rs*Wf[ow+c] + Wf[ob+c], dy*rs*Wf[ow+c+1] + Wf[ob+c+1]);
}

struct Srcs { const void* p[22]; };

// K-1: zero the padded bf16 xproj weight block (4 streams x 64 rows x 256)
__global__ void k_xwpad(unsigned* __restrict__ xw32){
  int i = blockIdx.x*256 + threadIdx.x;     // 32768 uints = 65536 shorts
  xw32[i] = 0u;
}

// K0: convert all weight tensors to f32 workspace (+ bf16 copies of GEMM weights)
__global__ void k_wcvt(Srcs s, float* __restrict__ ws,
                       unsigned short* __restrict__ wip, unsigned short* __restrict__ wob,
                       unsigned short* __restrict__ xw){
  bool isbf = bfmode(s.p[0]);
  int idx = blockIdx.x*256 + threadIdx.x;
  if(idx >= NW_RAW) return;
  int t = 0;
  while(t < 21 && idx >= c_woff[t+1]) t++;
  int j = idx - c_woff[t];
  if(j >= c_wsz[t]) return;  // padding gap
  float v = isbf ? bfu2f(((const unsigned short*)s.p[t])[j]) : ((const float*)s.p[t])[j];
  ws[idx] = v;
  if(t==11)      wip[j]         = f2bfu(v);   // in_proj_w
  else if(t==12) wip[65536+j]   = f2bfu(v);   // in_proj1_w
  else if(t==13) wip[98304+j]   = f2bfu(v);   // in_proj2_w
  else if(t==21) wob[j]         = f2bfu(v);   // out_w
  else if(t==16){                             // xproj_w -> padded [s][64][256]
    int sid = j / 10240, rem = j % 10240;
    xw[((size_t)sid*64 + rem/256)*256 + (rem%256)] = f2bfu(v);
  }
}

// K1: fusion_resi = fusion + fusion_resi -> out1(f32); xf(bf16) = ln1(ln1(fr))
__global__ void k_fuse(const void* fus, const void* fres, const void* ln1raw,
                       float* __restrict__ ws, float* __restrict__ outf,
                       unsigned short* __restrict__ xbf){
  bool isbf = bfmode(ln1raw);
  int lane = threadIdx.x & 63, wv = threadIdx.x >> 6;
  int row = blockIdx.x*4 + wv;              // 16384 rows
  int base = row*CC;
  float2 a = ldin2(fus, base+2*lane, isbf);
  float2 b = ldin2(fres, base+2*lane, isbf);
  float2 fr = make_float2(a.x+b.x, a.y+b.y);
  *(float2*)(outf + BLC + base + 2*lane) = fr;      // output 1 = fusion_resi (f32)
  float2 y = ln_wave(fr, ws, OW_LN1W, OW_LN1B, lane);
  y = ln_wave(y, ws, OW_LN1W, OW_LN1B, lane);
  unsigned pk = (unsigned)f2bfu(y.x) | ((unsigned)f2bfu(y.y)<<16);
  *(unsigned*)&xbf[base + 2*lane] = pk;
}

// K2a: per-pixel channel mean/max of I1 (ten=0) and I2 (ten=1)
__global__ void k_meanmax(const void* I1, const void* I2, const void* ln1raw, float* __restrict__ ws){
  bool isbf = bfmode(ln1raw);
  int lane = threadIdx.x & 63, wv = threadIdx.x >> 6;
  int g = blockIdx.x*4 + wv;                // 32768 waves
  int ten = g & 1, row = g >> 1;
  const void* src = ten ? I2 : I1;
  float2 x = ldin2(src, row*CC + 2*lane, isbf);
  float sm = wsum(x.x + x.y) * (1.f/(float)CC);
  float mx = wmaxr(fmaxf(x.x, x.y));
  if(lane == 0){
    int b = row >> 12, l = row & 4095;
    float* mt = ws + O_M + (size_t)ten*(BB*2*LLn);
    mt[(size_t)b*2*LLn + l] = sm;
    mt[(size_t)b*2*LLn + LLn + l] = mx;
  }
}

// K2b: 5x5 conv (2ch->1) + sigmoid -> s1,s2
__global__ void k_spconv(float* __restrict__ ws){
  int idx = blockIdx.x*256 + threadIdx.x;   // 32768
  int ten = idx >> 14, b = (idx>>12)&3, l = idx & 4095;
  int h = l >> 6, w = l & 63;
  const float* mt = ws + O_M + (size_t)ten*(BB*2*LLn) + (size_t)b*2*LLn;
  float acc = 0.f;
  for(int ci=0; ci<2; ci++)
    for(int kh=0; kh<5; kh++){
      int hh = h + kh - 2; if((unsigned)hh >= 64u) continue;
      for(int kw=0; kw<5; kw++){
        int wn = w + kw - 2; if((unsigned)wn >= 64u) continue;
        acc += mt[(size_t)ci*LLn + hh*64 + wn] * ws[OW_SPW + ci*25 + kh*5 + kw];
      }
    }
  ws[O_S + (size_t)ten*(BB*LLn) + (size_t)b*LLn + l] = sigf(acc);
}

// K2c: e1(bf16) = ln2(ln2(I2*s2)), e2(bf16) = ln3(ln3(I1*s1))
__global__ void k_escale(const void* I1, const void* I2, const void* ln1raw,
                         float* __restrict__ ws, unsigned short* __restrict__ xbf){
  bool isbf = bfmode(ln1raw);
  int lane = threadIdx.x & 63, wv = threadIdx.x >> 6;
  int g = blockIdx.x*4 + wv;
  int ten = g & 1, row = g >> 1;            // ten0: e1 from I2; ten1: e2 from I1
  const void* src = ten ? I1 : I2;
  float sc = ws[O_S + (ten ? 0 : (size_t)BB*LLn) + row];
  float2 x = ldin2(src, row*CC + 2*lane, isbf);
  x.x *= sc; x.y *= sc;
  int ow = ten ? OW_LN3W : OW_LN2W, ob = ten ? OW_LN3B : OW_LN2B;
  float2 y = ln_wave(x, ws, ow, ob, lane);
  y = ln_wave(y, ws, ow, ob, lane);
  unsigned short* eb = xbf + (ten ? 2*BLC : BLC);
  unsigned pk = (unsigned)f2bfu(y.x) | ((unsigned)f2bfu(y.y)<<16);
  *(unsigned*)&eb[row*CC + 2*lane] = pk;
}

// K3: bf16 MFMA GEMM  out[m,n] = sum_k A[m,k]*W[n,k].
// 64x64 tile, 4 waves; 16x16x32 MFMA; XOR-swizzled LDS.
// mode 0: f32 out (n<N guard). mode 1: in-proj split u(bf16)/z(f32). mode 3: bf16 out.
__global__ __launch_bounds__(256) void k_gemm_bf(const unsigned short* __restrict__ Abf,
    const unsigned short* __restrict__ Wbf, float* __restrict__ out,
    int Kd, int N, int mode, unsigned short* __restrict__ ub16, float* __restrict__ z){
  __shared__ unsigned short As[64*64];
  __shared__ unsigned short Bs[64*64];
  const int tid = threadIdx.x, lane = tid & 63, w = tid >> 6;
  const int n0 = blockIdx.x*64, m0 = blockIdx.y*64;
  const int g = lane >> 4, rlo = lane & 15;
  f32x4 acc[4];
#pragma unroll
  for(int i=0;i<4;i++) acc[i] = (f32x4){0.f,0.f,0.f,0.f};
  const int nk = Kd >> 6;
  for(int kt=0; kt<nk; kt++){
#pragma unroll
    for(int it=0; it<2; it++){               // stage 64x64 bf16 A and B tiles
      int idx = it*256 + tid, r = idx>>3, c = idx&7;
      uint4 av = *(const uint4*)&Abf[(size_t)(m0+r)*Kd + kt*64 + c*8];
      uint4 bv = *(const uint4*)&Wbf[(size_t)(n0+r)*Kd + kt*64 + c*8];
      int sw = (c*16) ^ ((r&7)<<4);          // bank swizzle (G4)
      *(uint4*)((char*)As + r*128 + sw) = av;
      *(uint4*)((char*)Bs + r*128 + sw) = bv;
    }
    __syncthreads();
#pragma unroll
    for(int ks=0; ks<2; ks++){
      int kb = ks*64 + g*16;
      int brow = w*16 + rlo;
      short8v bf = *(short8v*)((char*)Bs + brow*128 + (kb ^ ((rlo&7)<<4)));
#pragma unroll
      for(int rt=0; rt<4; rt++){
        int arow = rt*16 + rlo;
        short8v af = *(short8v*)((char*)As + arow*128 + (kb ^ ((rlo&7)<<4)));
        acc[rt] = __builtin_amdgcn_mfma_f32_16x16x32_bf16(af, bf, acc[rt], 0, 0, 0);
      }
    }
    __syncthreads();
  }
#pragma unroll
  for(int rt=0; rt<4; rt++){
#pragma unroll
    for(int j=0; j<4; j++){
      int m = m0 + rt*16 + g*4 + j;          // D: row=(lane>>4)*4+reg, col=lane&15 [m89]
      int n = n0 + w*16 + rlo;
      float val = acc[rt][j];
      if(mode == 1){                          // in-proj split: u0 bf16 / z f32
        int b = m >> 12, l = m & (LLn-1);
        if(n < DI) ub16[((size_t)b*LLn + l)*DI + n] = f2bfu(val);
        else       z[((size_t)b*LLn + l)*DI + (n-DI)] = val;
      } else if(mode == 3){
        ub16[(size_t)m*N + n] = f2bfu(val);
      } else {
        if(n < N) out[(size_t)m*N + n] = val;
      }
    }
  }
}

// K4+K5 fused: causal dwconv(K=4)+SiLU computed during A-staging of the xproj GEMM.
// uc written to global (for scan) AND staged to LDS for MFMA. proj(bf16)[65536,40] = uc @ xw[s]^T.
__global__ __launch_bounds__(256) void k_cxgemm(const float* __restrict__ ws,
    const unsigned short* __restrict__ ubf, unsigned short* __restrict__ ucbf,
    const unsigned short* __restrict__ xwbf, unsigned short* __restrict__ pbf){
  __shared__ unsigned short As[64*64];
  __shared__ unsigned short Bs[64*64];
  __shared__ float cwl[DI*4 + DI];          // conv weights + bias for this stream (5 KB)
  const int tid = threadIdx.x, lane = tid & 63, w = tid >> 6;
  const int m0 = blockIdx.y*64;
  const int sb = m0 >> 12, s = sb >> 2, b = sb & 3, l0 = m0 & 4095;
  const int g = lane >> 4, rlo = lane & 15;
  const bool rev = (s == 1);
  const unsigned short* ub = ubf + (rev ? (size_t)b*LLn : (size_t)sb*LLn)*DI;
  const unsigned short* Wbf = xwbf + (size_t)s*(64*256);
#pragma unroll
  for(int i=0;i<5;i++){
    int idx = i*256 + tid;
    if(idx < DI*4)      cwl[idx] = ws[OW_CVW + (size_t)s*DI*4 + idx];
    else if(idx < DI*5) cwl[idx] = ws[OW_CVB + s*DI + (idx - DI*4)];
  }
  __syncthreads();
  f32x4 acc[4];
#pragma unroll
  for(int i=0;i<4;i++) acc[i] = (f32x4){0.f,0.f,0.f,0.f};
#pragma unroll
  for(int kt=0; kt<4; kt++){
#pragma unroll
    for(int it=0; it<2; it++){
      int idx = it*256 + tid, r = idx>>3, c = idx&7;
      int ch0 = kt*64 + c*8;
      int l = l0 + r;
      float4 ulo[4], uhi[4];
#pragma unroll
      for(int k=0;k<4;k++){
        int lm = l - 3 + k;
        if(lm < 0){ ulo[k]=make_float4(0,0,0,0); uhi[k]=make_float4(0,0,0,0); }
        else {
          uint4 uv = *(const uint4*)&ub[(size_t)(rev?(LLn-1-lm):lm)*DI + ch0];
          ulo[k] = bf4(make_uint2(uv.x,uv.y)); uhi[k] = bf4(make_uint2(uv.z,uv.w));
        }
      }
      float res[8];
#pragma unroll
      for(int j=0;j<4;j++){
        const float* cw = &cwl[(ch0+j)*4];
        float a = cwl[DI*4 + ch0 + j];
        float v0 = (&ulo[0].x)[j], v1 = (&ulo[1].x)[j], v2 = (&ulo[2].x)[j], v3 = (&ulo[3].x)[j];
        a += cw[0]*v0 + cw[1]*v1 + cw[2]*v2 + cw[3]*v3;
        res[j] = a * sigf(a);
      }
#pragma unroll
      for(int j=0;j<4;j++){
        const float* cw = &cwl[(ch0+4+j)*4];
        float a = cwl[DI*4 + ch0 + 4 + j];
        float v0 = (&uhi[0].x)[j], v1 = (&uhi[1].x)[j], v2 = (&uhi[2].x)[j], v3 = (&uhi[3].x)[j];
        a += cw[0]*v0 + cw[1]*v1 + cw[2]*v2 + cw[3]*v3;
        res[4+j] = a * sigf(a);
      }
      uint2 plo = pk4(make_float4(res[0],res[1],res[2],res[3]));
      uint2 phi = pk4(make_float4(res[4],res[5],res[6],res[7]));
      uint4 pk = make_uint4(plo.x, plo.y, phi.x, phi.y);
      *(uint4*)&ucbf[((size_t)sb*LLn + l)*DI + ch0] = pk;          // uc for the scan
      int sw = (c*16) ^ ((r&7)<<4);
      *(uint4*)((char*)As + r*128 + sw) = pk;
      uint4 bv = *(const uint4*)&Wbf[(size_t)r*256 + kt*64 + c*8];
      *(uint4*)((char*)Bs + r*128 + sw) = bv;
    }
    __syncthreads();
#pragma unroll
    for(int ks=0; ks<2; ks++){
      int kb = ks*64 + g*16;
      int brow = w*16 + rlo;
      short8v bf = *(short8v*)((char*)Bs + brow*128 + (kb ^ ((rlo&7)<<4)));
#pragma unroll
      for(int rt=0; rt<4; rt++){
        int arow = rt*16 + rlo;
        short8v af = *(short8v*)((char*)As + arow*128 + (kb ^ ((rlo&7)<<4)));
        acc[rt] = __builtin_amdgcn_mfma_f32_16x16x32_bf16(af, bf, acc[rt], 0, 0, 0);
      }
    }
    __syncthreads();
  }
#pragma unroll
  for(int rt=0; rt<4; rt++){
#pragma unroll
    for(int j=0; j<4; j++){
      int m = m0 + rt*16 + g*4 + j;
      int n = w*16 + rlo;
      if(n < PP) pbf[(size_t)m*PP + n] = f2bfu(acc[rt][j]);
    }
  }
}

// K6/K8: chunk-parallel selective scan (CT=64; f32 LDS staging of bf16 proj rows).
// 128 threads/block; each thread handles TWO d-columns (d, d+128) so the 10
// wave-uniform ds_read_b128/step serve 2x the work (halves the LDS-issue bound).
// PH3=false: local scan -> Hend,Sdt. PH3=true: re-run with h_in, emit y (bf16).
template<bool PH3>
__global__ __launch_bounds__(128) void k_scan(float* __restrict__ ws,
                                              const unsigned short* __restrict__ ucbf,
                                              const unsigned short* __restrict__ pbf){
  __shared__ float pl[CT*PP];               // 2560 floats = 10 KB
  int ch = blockIdx.x & (NCH-1), sb = blockIdx.x >> 6, s = sb >> 2;
  int t = threadIdx.x;                      // 0..127
  int d0 = t, d1 = t + 128;
  size_t prow = ((size_t)sb*LLn + (size_t)ch*CT)*PP;
#pragma unroll
  for(int i=0;i<20;i++){ int idx = i*128 + t; pl[idx] = bfu2f(pbf[prow + idx]); }
  __syncthreads();
  unsigned short* ybf = (unsigned short*)(ws + O_U);   // y overwrites dead u (bf16)
  unsigned short* Hb  = (unsigned short*)(ws + O_H);   // bf16 chunk states
  unsigned short* Sdb = (unsigned short*)(ws + O_SDT); // bf16 chunk dt sums
  float4 dtwA0 = *(const float4*)&ws[OW_DTW + ((size_t)s*DI + d0)*RR];
  float4 dtwA1 = *(const float4*)&ws[OW_DTW + ((size_t)s*DI + d0)*RR + 4];
  float4 dtwB0 = *(const float4*)&ws[OW_DTW + ((size_t)s*DI + d1)*RR];
  float4 dtwB1 = *(const float4*)&ws[OW_DTW + ((size_t)s*DI + d1)*RR + 4];
  float dtbA = ws[OW_DTB + s*DI + d0];
  float dtbB = ws[OW_DTB + s*DI + d1];
  float an2A[NS], an2B[NS]; bool fast = true;
#pragma unroll
  for(int n=0;n<NS;n++){
    float aA = -__expf(ws[OW_ALOG + ((size_t)s*DI + d0)*NS + n]);
    float aB = -__expf(ws[OW_ALOG + ((size_t)s*DI + d1)*NS + n]);
    an2A[n] = aA * 1.44269504f; an2B[n] = aB * 1.44269504f;
    fast = fast && (fabsf(aA + (float)(n+1)) < 1e-4f) && (fabsf(aB + (float)(n+1)) < 1e-4f);
  }
  float4 hA0,hA1,hA2,hA3, hB0,hB1,hB2,hB3;
  size_t hbA = (((size_t)sb*NCH + ch)*DI + d0)*NS;      // short index
  size_t hbB = (((size_t)sb*NCH + ch)*DI + d1)*NS;
  if(PH3){
    uint4 ha = *(const uint4*)&Hb[hbA]; uint4 hc = *(const uint4*)&Hb[hbA+8];
    hA0 = bf4(make_uint2(ha.x,ha.y)); hA1 = bf4(make_uint2(ha.z,ha.w));
    hA2 = bf4(make_uint2(hc.x,hc.y)); hA3 = bf4(make_uint2(hc.z,hc.w));
    uint4 hb2 = *(const uint4*)&Hb[hbB]; uint4 hd = *(const uint4*)&Hb[hbB+8];
    hB0 = bf4(make_uint2(hb2.x,hb2.y)); hB1 = bf4(make_uint2(hb2.z,hb2.w));
    hB2 = bf4(make_uint2(hd.x,hd.y)); hB3 = bf4(make_uint2(hd.z,hd.w));
  } else {
    hA0=hA1=hA2=hA3=make_float4(0.f,0.f,0.f,0.f);
    hB0=hB1=hB2=hB3=make_float4(0.f,0.f,0.f,0.f);
  }
  float dskA = PH3 ? ws[OW_DSK + s*DI + d0] : 0.f;
  float dskB = PH3 ? ws[OW_DSK + s*DI + d1] : 0.f;
  float sdtA = 0.f, sdtB = 0.f;
  size_t ubase = ((size_t)sb*LLn + (size_t)ch*CT)*DI;
  if(fast){
    for(int ll=0; ll<CT; ll++){
      const float* pr = &pl[ll*PP];
      float4 p0 = *(const float4*)pr, p1 = *(const float4*)(pr+4);
      float4 B0 = *(const float4*)(pr+8),  B1 = *(const float4*)(pr+12),
             B2 = *(const float4*)(pr+16), B3 = *(const float4*)(pr+20);
      // ---- d0 ----
      float xA = dtbA + p0.x*dtwA0.x + p0.y*dtwA0.y + p0.z*dtwA0.z + p0.w*dtwA0.w
                      + p1.x*dtwA1.x + p1.y*dtwA1.y + p1.z*dtwA1.z + p1.w*dtwA1.w;
      float dtA = (xA > 15.f) ? xA : __logf(1.f + __expf(xA));
      float utA = bfu2f(ucbf[ubase + (size_t)ll*DI + d0]);
      float duA = dtA*utA;
      float eA = __expf(-dtA); float eA2 = eA*eA, eA4 = eA2*eA2;
      float4 daA = make_float4(eA, eA2, eA2*eA, eA4);
      // ---- d1 ----
      float xB = dtbB + p0.x*dtwB0.x + p0.y*dtwB0.y + p0.z*dtwB0.z + p0.w*dtwB0.w
                      + p1.x*dtwB1.x + p1.y*dtwB1.y + p1.z*dtwB1.z + p1.w*dtwB1.w;
      float dtB = (xB > 15.f) ? xB : __logf(1.f + __expf(xB));
      float utB = bfu2f(ucbf[ubase + (size_t)ll*DI + d1]);
      float duB = dtB*utB;
      float eB = __expf(-dtB); float eB2 = eB*eB, eB4 = eB2*eB2;
      float4 daB = make_float4(eB, eB2, eB2*eB, eB4);
      if(PH3){
        float4 C0 = *(const float4*)(pr+24), C1 = *(const float4*)(pr+28),
               C2 = *(const float4*)(pr+32), C3 = *(const float4*)(pr+36);
        float yA, yB;
        hA0.x = fmaf(hA0.x, daA.x, duA*B0.x); yA  = hA0.x*C0.x;
        hA0.y = fmaf(hA0.y, daA.y, duA*B0.y); yA = fmaf(hA0.y, C0.y, yA);
        hA0.z = fmaf(hA0.z, daA.z, duA*B0.z); yA = fmaf(hA0.z, C0.z, yA);
        hA0.w = fmaf(hA0.w, daA.w, duA*B0.w); yA = fmaf(hA0.w, C0.w, yA);
        daA.x *= eA4; daA.y *= eA4; daA.z *= eA4; daA.w *= eA4;
        hA1.x = fmaf(hA1.x, daA.x, duA*B1.x); yA = fmaf(hA1.x, C1.x, yA);
        hA1.y = fmaf(hA1.y, daA.y, duA*B1.y); yA = fmaf(hA1.y, C1.y, yA);
        hA1.z = fmaf(hA1.z, daA.z, duA*B1.z); yA = fmaf(hA1.z, C1.z, yA);
        hA1.w = fmaf(hA1.w, daA.w, duA*B1.w); yA = fmaf(hA1.w, C1.w, yA);
        daA.x *= eA4; daA.y *= eA4; daA.z *= eA4; daA.w *= eA4;
        hA2.x = fmaf(hA2.x, daA.x, duA*B2.x); yA = fmaf(hA2.x, C2.x, yA);
        hA2.y = fmaf(hA2.y, daA.y, duA*B2.y); yA = fmaf(hA2.y, C2.y, yA);
        hA2.z = fmaf(hA2.z, daA.z, duA*B2.z); yA = fmaf(hA2.z, C2.z, yA);
        hA2.w = fmaf(hA2.w, daA.w, duA*B2.w); yA = fmaf(hA2.w, C2.w, yA);
        daA.x *= eA4; daA.y *= eA4; daA.z *= eA4; daA.w *= eA4;
        hA3.x = fmaf(hA3.x, daA.x, duA*B3.x); yA = fmaf(hA3.x, C3.x, yA);
        hA3.y = fmaf(hA3.y, daA.y, duA*B3.y); yA = fmaf(hA3.y, C3.y, yA);
        hA3.z = fmaf(hA3.z, daA.z, duA*B3.z); yA = fmaf(hA3.z, C3.z, yA);
        hA3.w = fmaf(hA3.w, daA.w, duA*B3.w); yA = fmaf(hA3.w, C3.w, yA);
        ybf[ubase + (size_t)ll*DI + d0] = f2bfu(yA + utA*dskA);
        hB0.x = fmaf(hB0.x, daB.x, duB*B0.x); yB  = hB0.x*C0.x;
        hB0.y = fmaf(hB0.y, daB.y, duB*B0.y); yB = fmaf(hB0.y, C0.y, yB);
        hB0.z = fmaf(hB0.z, daB.z, duB*B0.z); yB = fmaf(hB0.z, C0.z, yB);
        hB0.w = fmaf(hB0.w, daB.w, duB*B0.w); yB = fmaf(hB0.w, C0.w, yB);
        daB.x *= eB4; daB.y *= eB4; daB.z *= eB4; daB.w *= eB4;
        hB1.x = fmaf(hB1.x, daB.x, duB*B1.x); yB = fmaf(hB1.x, C1.x, yB);
        hB1.y = fmaf(hB1.y, daB.y, duB*B1.y); yB = fmaf(hB1.y, C1.y, yB);
        hB1.z = fmaf(hB1.z, daB.z, duB*B1.z); yB = fmaf(hB1.z, C1.z, yB);
        hB1.w = fmaf(hB1.w, daB.w, duB*B1.w); yB = fmaf(hB1.w, C1.w, yB);
        daB.x *= eB4; daB.y *= eB4; daB.z *= eB4; daB.w *= eB4;
        hB2.x = fmaf(hB2.x, daB.x, duB*B2.x); yB = fmaf(hB2.x, C2.x, yB);
        hB2.y = fmaf(hB2.y, daB.y, duB*B2.y); yB = fmaf(hB2.y, C2.y, yB);
        hB2.z = fmaf(hB2.z, daB.z, duB*B2.z); yB = fmaf(hB2.z, C2.z, yB);
        hB2.w = fmaf(hB2.w, daB.w, duB*B2.w); yB = fmaf(hB2.w, C2.w, yB);
        daB.x *= eB4; daB.y *= eB4; daB.z *= eB4; daB.w *= eB4;
        hB3.x = fmaf(hB3.x, daB.x, duB*B3.x); yB = fmaf(hB3.x, C3.x, yB);
        hB3.y = fmaf(hB3.y, daB.y, duB*B3.y); yB = fmaf(hB3.y, C3.y, yB);
        hB3.z = fmaf(hB3.z, daB.z, duB*B3.z); yB = fmaf(hB3.z, C3.z, yB);
        hB3.w = fmaf(hB3.w, daB.w, duB*B3.w); yB = fmaf(hB3.w, C3.w, yB);
        ybf[ubase + (size_t)ll*DI + d1] = f2bfu(yB + utB*dskB);
      } else {
        hA0.x = fmaf(hA0.x, daA.x, duA*B0.x); hA0.y = fmaf(hA0.y, daA.y, duA*B0.y);
        hA0.z = fmaf(hA0.z, daA.z, duA*B0.z); hA0.w = fmaf(hA0.w, daA.w, duA*B0.w);
        daA.x *= eA4; daA.y *= eA4; daA.z *= eA4; daA.w *= eA4;
        hA1.x = fmaf(hA1.x, daA.x, duA*B1.x); hA1.y = fmaf(hA1.y, daA.y, duA*B1.y);
        hA1.z = fmaf(hA1.z, daA.z, duA*B1.z); hA1.w = fmaf(hA1.w, daA.w, duA*B1.w);
        daA.x *= eA4; daA.y *= eA4; daA.z *= eA4; daA.w *= eA4;
        hA2.x = fmaf(hA2.x, daA.x, duA*B2.x); hA2.y = fmaf(hA2.y, daA.y, duA*B2.y);
        hA2.z = fmaf(hA2.z, daA.z, duA*B2.z); hA2.w = fmaf(hA2.w, daA.w, duA*B2.w);
        daA.x *= eA4; daA.y *= eA4; daA.z *= eA4; daA.w *= eA4;
        hA3.x = fmaf(hA3.x, daA.x, duA*B3.x); hA3.y = fmaf(hA3.y, daA.y, duA*B3.y);
        hA3.z = fmaf(hA3.z, daA.z, duA*B3.z); hA3.w = fmaf(hA3.w, daA.w, duA*B3.w);
        sdtA += dtA;
        hB0.x = fmaf(hB0.x, daB.x, duB*B0.x); hB0.y = fmaf(hB0.y, daB.y, duB*B0.y);
        hB0.z = fmaf(hB0.z, daB.z, duB*B0.z); hB0.w = fmaf(hB0.w, daB.w, duB*B0.w);
        daB.x *= eB4; daB.y *= eB4; daB.z *= eB4; daB.w *= eB4;
        hB1.x = fmaf(hB1.x, daB.x, duB*B1.x); hB1.y = fmaf(hB1.y, daB.y, duB*B1.y);
        hB1.z = fmaf(hB1.z, daB.z, duB*B1.z); hB1.w = fmaf(hB1.w, daB.w, duB*B1.w);
        daB.x *= eB4; daB.y *= eB4; daB.z *= eB4; daB.w *= eB4;
        hB2.x = fmaf(hB2.x, daB.x, duB*B2.x); hB2.y = fmaf(hB2.y, daB.y, duB*B2.y);
        hB2.z = fmaf(hB2.z, daB.z, duB*B2.z); hB2.w = fmaf(hB2.w, daB.w, duB*B2.w);
        daB.x *= eB4; daB.y *= eB4; daB.z *= eB4; daB.w *= eB4;
        hB3.x = fmaf(hB3.x, daB.x, duB*B3.x); hB3.y = fmaf(hB3.y, daB.y, duB*B3.y);
        hB3.z = fmaf(hB3.z, daB.z, duB*B3.z); hB3.w = fmaf(hB3.w, daB.w, duB*B3.w);
        sdtB += dtB;
      }
    }
  } else {
    float hA[NS], hB[NS];
    hA[0]=hA0.x;hA[1]=hA0.y;hA[2]=hA0.z;hA[3]=hA0.w; hA[4]=hA1.x;hA[5]=hA1.y;hA[6]=hA1.z;hA[7]=hA1.w;
    hA[8]=hA2.x;hA[9]=hA2.y;hA[10]=hA2.z;hA[11]=hA2.w; hA[12]=hA3.x;hA[13]=hA3.y;hA[14]=hA3.z;hA[15]=hA3.w;
    hB[0]=hB0.x;hB[1]=hB0.y;hB[2]=hB0.z;hB[3]=hB0.w; hB[4]=hB1.x;hB[5]=hB1.y;hB[6]=hB1.z;hB[7]=hB1.w;
    hB[8]=hB2.x;hB[9]=hB2.y;hB[10]=hB2.z;hB[11]=hB2.w; hB[12]=hB3.x;hB[13]=hB3.y;hB[14]=hB3.z;hB[15]=hB3.w;
    for(int ll=0; ll<CT; ll++){
      const float* pr = &pl[ll*PP];
      float xA = dtbA, xB = dtbB;
      xA += pr[0]*dtwA0.x + pr[1]*dtwA0.y + pr[2]*dtwA0.z + pr[3]*dtwA0.w;
      xA += pr[4]*dtwA1.x + pr[5]*dtwA1.y + pr[6]*dtwA1.z + pr[7]*dtwA1.w;
      xB += pr[0]*dtwB0.x + pr[1]*dtwB0.y + pr[2]*dtwB0.z + pr[3]*dtwB0.w;
      xB += pr[4]*dtwB1.x + pr[5]*dtwB1.y + pr[6]*dtwB1.z + pr[7]*dtwB1.w;
      float dtA = (xA > 15.f) ? xA : __logf(1.f + __expf(xA));
      float dtB = (xB > 15.f) ? xB : __logf(1.f + __expf(xB));
      float utA = bfu2f(ucbf[ubase + (size_t)ll*DI + d0]);
      float utB = bfu2f(ucbf[ubase + (size_t)ll*DI + d1]);
      float duA = dtA*utA, duB = dtB*utB;
      if(PH3){
        float yA = 0.f, yB = 0.f;
#pragma unroll
        for(int n=0;n<NS;n++){
          float daA = exp2f(an2A[n]*dtA); hA[n] = hA[n]*daA + duA*pr[RR+n]; yA += hA[n]*pr[RR+NS+n];
          float daB = exp2f(an2B[n]*dtB); hB[n] = hB[n]*daB + duB*pr[RR+n]; yB += hB[n]*pr[RR+NS+n];
        }
        ybf[ubase + (size_t)ll*DI + d0] = f2bfu(yA + utA*dskA);
        ybf[ubase + (size_t)ll*DI + d1] = f2bfu(yB + utB*dskB);
      } else {
#pragma unroll
        for(int n=0;n<NS;n++){
          float daA = exp2f(an2A[n]*dtA); hA[n] = hA[n]*daA + duA*pr[RR+n];
          float daB = exp2f(an2B[n]*dtB); hB[n] = hB[n]*daB + duB*pr[RR+n];
        }
        sdtA += dtA; sdtB += dtB;
      }
    }
    hA0=make_float4(hA[0],hA[1],hA[2],hA[3]); hA1=make_float4(hA[4],hA[5],hA[6],hA[7]);
    hA2=make_float4(hA[8],hA[9],hA[10],hA[11]); hA3=make_float4(hA[12],hA[13],hA[14],hA[15]);
    hB0=make_float4(hB[0],hB[1],hB[2],hB[3]); hB1=make_float4(hB[4],hB[5],hB[6],hB[7]);
    hB2=make_float4(hB[8],hB[9],hB[10],hB[11]); hB3=make_float4(hB[12],hB[13],hB[14],hB[15]);
  }
  if(!PH3){
    uint2 a = pk4(hA0), b2 = pk4(hA1), c = pk4(hA2), dd = pk4(hA3);
    *(uint4*)&Hb[hbA]   = make_uint4(a.x,a.y,b2.x,b2.y);
    *(uint4*)&Hb[hbA+8] = make_uint4(c.x,c.y,dd.x,dd.y);
    uint2 a2 = pk4(hB0), b3 = pk4(hB1), c2 = pk4(hB2), d2 = pk4(hB3);
    *(uint4*)&Hb[hbB]   = make_uint4(a2.x,a2.y,b3.x,b3.y);
    *(uint4*)&Hb[hbB+8] = make_uint4(c2.x,c2.y,d2.x,d2.y);
    Sdb[((size_t)sb*NCH + ch)*DI + d0] = f2bfu(sdtA);
    Sdb[((size_t)sb*NCH + ch)*DI + d1] = f2bfu(sdtB);
  }
}

// K7: combine chunk boundary states (bf16 H/Sdt, coalesced): Hend -> Hin, in place
__global__ void k_scan2(float* __restrict__ ws){
  int t = blockIdx.x*256 + threadIdx.x;     // 65536 = S*B*DI*NS
  int n = t & (NS-1), d = (t>>4) & (DI-1), sb = t >> 12, s = sb >> 2;
  float an2 = -__expf(ws[OW_ALOG + ((size_t)s*DI + d)*NS + n]) * 1.44269504f;
  float hin = 0.f;
  unsigned short* Hb  = (unsigned short*)(ws + O_H);
  const unsigned short* Sdb = (const unsigned short*)(ws + O_SDT);
  for(int c=0;c<NCH;c++){
    size_t hi = (((size_t)sb*NCH + c)*DI + d)*NS + n;
    float he = bfu2f(Hb[hi]);
    float sd = bfu2f(Sdb[((size_t)sb*NCH + c)*DI + d]);
    Hb[hi] = f2bfu(hin);
    hin = he + exp2f(an2*sd)*hin;
  }
}

// K9: combine 4 streams (stream1 re-reversed, bf16 y), gate with silu(z) -> gbf (bf16)
__global__ void k_gate(float* __restrict__ ws, unsigned short* __restrict__ gbf){
  int t = blockIdx.x*256 + threadIdx.x;     // BLD/4
  int d4 = t & 63, l = (t>>6)&4095, b = t>>18;
  int d0 = d4*4;
  const unsigned short* ybf = (const unsigned short*)(ws + O_U);
  size_t i0 = ((size_t)(0*BB+b)*LLn + l)*DI + d0;
  size_t i1 = ((size_t)(1*BB+b)*LLn + (LLn-1-l))*DI + d0;
  size_t i2 = ((size_t)(2*BB+b)*LLn + l)*DI + d0;
  size_t i3 = ((size_t)(3*BB+b)*LLn + l)*DI + d0;
  float4 a = bf4(*(const uint2*)&ybf[i0]);
  float4 bb4 = bf4(*(const uint2*)&ybf[i1]);
  float4 c = bf4(*(const uint2*)&ybf[i2]);
  float4 dd = bf4(*(const uint2*)&ybf[i3]);
  size_t zi = ((size_t)b*LLn + l)*DI + d0;
  float4 zv = *(const float4*)&ws[O_Z + zi];
  float4 g;
  g.x = (a.x+bb4.x+c.x+dd.x) * (zv.x*sigf(zv.x));
  g.y = (a.y+bb4.y+c.y+dd.y) * (zv.y*sigf(zv.y));
  g.z = (a.z+bb4.z+c.z+dd.z) * (zv.z*sigf(zv.z));
  g.w = (a.w+bb4.w+c.w+dd.w) * (zv.w*sigf(zv.w));
  *(uint2*)&gbf[zi] = pk4(g);
}

// K10: partial spatial mean/max of gf per (b, 128-row segment)
__global__ void k_redmm(float* __restrict__ ws){
  int b = blockIdx.x >> 5, seg = blockIdx.x & 31, c = threadIdx.x; // 128 threads
  const float* gf = ws + O_GF;
  float sm = 0.f, mx = -3e38f;
  size_t base = ((size_t)b*LLn + (size_t)seg*128)*CC + c;
  for(int i=0;i<128;i++){ float v = gf[base + (size_t)i*CC]; sm += v; mx = fmaxf(mx, v); }
  ws[O_PART + ((size_t)b*32 + seg)*CC + c] = sm;
  ws[O_PART + (size_t)BB*32*CC + ((size_t)b*32 + seg)*CC + c] = mx;
}

// K11: channel attention MLP -> sig[b,c]
__global__ void k_catt(float* __restrict__ ws){
  __shared__ float vm[CC], vx[CC], hm[32], hx[32];
  int b = blockIdx.x, c = threadIdx.x;      // 128 threads
  float sm = 0.f, mx = -3e38f;
  for(int seg=0;seg<32;seg++){
    sm += ws[O_PART + ((size_t)b*32+seg)*CC + c];
    mx = fmaxf(mx, ws[O_PART + (size_t)BB*32*CC + ((size_t)b*32+seg)*CC + c]);
  }
  vm[c] = sm * (1.f/(float)LLn); vx[c] = mx;
  __syncthreads();
  if(c < 32){
    float am = 0.f, ax = 0.f;
    for(int k=0;k<CC;k++){ float w1 = ws[OW_CAW1 + c*CC + k]; am += vm[k]*w1; ax += vx[k]*w1; }
    hm[c] = fmaxf(am, 0.f); hx[c] = fmaxf(ax, 0.f);
  }
  __syncthreads();
  float om = 0.f, ox = 0.f;
  for(int k=0;k<32;k++){ float w2 = ws[OW_CAW2 + c*32 + k]; om += hm[k]*w2; ox += hx[k]*w2; }
  ws[O_SIG + (size_t)b*CC + c] = sigf(om + ox);
}

// K12: f4 = gf^2*sig; out0 = dwconv3x3(f4) + dw_b + f4  (f32)
__global__ void k_final(float* __restrict__ ws, float* __restrict__ outf){
  int t = blockIdx.x*256 + threadIdx.x;     // B*L*C/4 = 524288
  int c4 = t & 31, l = (t>>5)&4095, b = t>>17;
  int h = l>>6, w = l&63;
  const float* gf = ws + O_GF;
  float4 sg = *(const float4*)&ws[O_SIG + (size_t)b*CC + c4*4];
  size_t rb = ((size_t)b*LLn)*CC;
  float4 gc = *(const float4*)&gf[rb + (size_t)l*CC + c4*4];
  float4 fc = make_float4(gc.x*gc.x*sg.x, gc.y*gc.y*sg.y, gc.z*gc.z*sg.z, gc.w*gc.w*sg.w);
  float4 acc = *(const float4*)&ws[OW_DWB + c4*4];
  float wv[4][9];
#pragma unroll
  for(int j=0;j<4;j++)
#pragma unroll
    for(int q=0;q<9;q++) wv[j][q] = ws[OW_DWW + (c4*4+j)*9 + q];
#pragma unroll
  for(int kh=0;kh<3;kh++){
    int hh = h + kh - 1; if((unsigned)hh >= 64u) continue;
#pragma unroll
    for(int kw=0;kw<3;kw++){
      int wn = w + kw - 1; if((unsigned)wn >= 64u) continue;
      float4 g = *(const float4*)&gf[rb + (size_t)(hh*64+wn)*CC + c4*4];
      int q = kh*3+kw;
      acc.x += wv[0][q]*g.x*g.x*sg.x;
      acc.y += wv[1][q]*g.y*g.y*sg.y;
      acc.z += wv[2][q]*g.z*g.z*sg.z;
      acc.w += wv[3][q]*g.w*g.w*sg.w;
    }
  }
  float4 o = make_float4(acc.x+fc.x, acc.y+fc.y, acc.z+fc.z, acc.w+fc.w);
  size_t ob = ((size_t)b*LLn + l)*CC + c4*4;
  *(float4*)&outf[ob] = o;                  // output 0 (f32)
}

extern "C" void kernel_launch(void* const* d_in, const int* in_sizes, int n_in,
                              void* d_out, int out_size, void* d_ws, size_t ws_size,
                              hipStream_t stream){
  (void)in_sizes; (void)n_in; (void)out_size;
  if(ws_size < WS_END*sizeof(float)) return;
  float* ws = (float*)d_ws;
  float* outf = (float*)d_out;              // f32 outputs (reference returns float32)
  const void* I1 = d_in[0]; const void* FRES = d_in[1];
  const void* I2 = d_in[2]; const void* FUS  = d_in[3];
  const void* LN1RAW = d_in[4];

  // bf16 aliases over dead-at-the-time f32 regions
  unsigned short* xbf   = (unsigned short*)(ws + O_H);    // xf [0,BLC), e1 [BLC,2BLC), e2 [2BLC,3BLC)
  unsigned short* gbf   = xbf;                            // gated, after scan (H dead)
  unsigned short* wipbf = (unsigned short*)(ws + O_GF);   // ipw | ip1w | ip2w (bf16)
  unsigned short* wobf  = (unsigned short*)(ws + O_PART); // out_w (bf16)
  unsigned short* xwbf  = (unsigned short*)(ws + O_XF);   // padded xproj weights [4][64][256] bf16
  unsigned short* ucbf  = (unsigned short*)(ws + O_UC);   // uc bf16 [S*B*L][256]
  unsigned short* ubf   = (unsigned short*)(ws + O_U);    // u bf16 [S*B*L][256]; later y bf16
  unsigned short* pbf   = (unsigned short*)(ws + O_PROJ); // proj bf16 [S*B*L][40]

  Srcs sr;
  for(int i=0;i<22;i++) sr.p[i] = d_in[4+i];
  k_xwpad<<<128, 256, 0, stream>>>((unsigned*)xwbf);
  k_wcvt<<<(NW_RAW+255)/256, 256, 0, stream>>>(sr, ws, wipbf, wobf, xwbf);
  k_fuse<<<4096, 256, 0, stream>>>(FUS, FRES, LN1RAW, ws, outf, xbf);
  k_meanmax<<<8192, 256, 0, stream>>>(I1, I2, LN1RAW, ws);
  k_spconv<<<128, 256, 0, stream>>>(ws);
  k_escale<<<8192, 256, 0, stream>>>(I1, I2, LN1RAW, ws, xbf);
  // MFMA GEMMs: in-proj (split u0 bf16 / z f32), e1->u2 bf16, e2->u3 bf16
  k_gemm_bf<<<dim3(8,256), 256, 0, stream>>>(xbf,         wipbf,       nullptr,      128, 512, 1, ubf,        ws+O_Z);
  k_gemm_bf<<<dim3(4,256), 256, 0, stream>>>(xbf+BLC,     wipbf+65536, nullptr,      128, 256, 3, ubf+2*BLD,  nullptr);
  k_gemm_bf<<<dim3(4,256), 256, 0, stream>>>(xbf+2*BLC,   wipbf+98304, nullptr,      128, 256, 3, ubf+3*BLD,  nullptr);
  // fused conv+SiLU+xproj GEMM: writes uc (bf16) and proj (bf16)
  k_cxgemm<<<dim3(1,1024), 256, 0, stream>>>(ws, ubf, ucbf, xwbf, pbf);
  k_scan<false><<<SS*BB*NCH, 128, 0, stream>>>(ws, ucbf, pbf);
  k_scan2<<<256, 256, 0, stream>>>(ws);
  k_scan<true><<<SS*BB*NCH, 128, 0, stream>>>(ws, ucbf, pbf);
  k_gate<<<4096, 256, 0, stream>>>(ws, gbf);
  // out-proj: gf = g @ out_w.T  (reads gbf at O_H, writes O_GF over dead wipbf)
  k_gemm_bf<<<dim3(2,256), 256, 0, stream>>>(gbf, wobf, ws+O_GF, 256, 128, 0, nullptr, nullptr);
  k_redmm<<<128, 128, 0, stream>>>(ws);
  k_catt<<<4, 128, 0, stream>>>(ws);
  k_final<<<2048, 256, 0, stream>>>(ws, outf);
}

// Round 16
// 243.480 us; speedup vs baseline: 1.1511x; 1.1511x over previous
//
#include <hip/hip_runtime.h>

#define DEVI __device__ __forceinline__

static constexpr int BB=4, CC=128, LLn=4096, DI=256, NS=16, RR=8, SS=4;
static constexpr int PP = RR + 2*NS;            // 40
static constexpr int CT = 64, NCH = LLn/CT;     // scan chunking: 64 chunks of 64
static constexpr int NCHF = 64;                 // layout sizing unit (unchanged)
static constexpr size_t BLC  = (size_t)BB*LLn*CC;    // 2,097,152
static constexpr size_t BLD  = (size_t)BB*LLn*DI;    // 4,194,304
static constexpr size_t SBLD = (size_t)SS*BLD;
static constexpr size_t SBLP = (size_t)SS*BB*LLn*PP;

// ---- weight offsets inside ws (floats), padded to multiples of 4 ----
static constexpr int OW_LN1W=0, OW_LN1B=128, OW_LN2W=256, OW_LN2B=384, OW_LN3W=512, OW_LN3B=640,
 OW_SPW=768, OW_CAW1=820, OW_CAW2=4916, OW_DWW=9012, OW_DWB=10164, OW_IPW=10292,
 OW_IP1W=75828, OW_IP2W=108596, OW_CVW=141364, OW_CVB=145460, OW_XPW=146484,
 OW_DTW=187444, OW_DTB=195636, OW_ALOG=196660, OW_DSK=213044, OW_OUTW=214068;
static constexpr int NW_RAW = 246836;   // last tensor end
static constexpr int NW_END = 246848;   // padded

__constant__ int c_woff[22] = {OW_LN1W,OW_LN1B,OW_LN2W,OW_LN2B,OW_LN3W,OW_LN3B,OW_SPW,OW_CAW1,
 OW_CAW2,OW_DWW,OW_DWB,OW_IPW,OW_IP1W,OW_IP2W,OW_CVW,OW_CVB,OW_XPW,OW_DTW,OW_DTB,OW_ALOG,
 OW_DSK,OW_OUTW};
__constant__ int c_wsz[22]  = {128,128,128,128,128,128,50,4096,4096,1152,128,65536,32768,32768,
 4096,1024,40960,8192,1024,16384,1024,32768};

// ---- workspace layout (float offsets) — byte-identical to round 13 ----
static constexpr size_t O_XF   = NW_END;              // aliased: bf16 padded xproj weights (4x64x256 shorts)
static constexpr size_t O_E1   = O_XF + BLC;          // (unused)
static constexpr size_t O_E2   = O_E1 + BLC;          // (unused)
static constexpr size_t O_Z    = O_E2 + BLC;          // z from in-proj (f32)
static constexpr size_t O_U    = O_Z + BLD;           // aliased: u streams bf16 (SBLD shorts); later y bf16
static constexpr size_t O_UC   = O_U + SBLD;          // aliased: uc in bf16 (SBLD shorts)
static constexpr size_t O_PROJ = O_UC + SBLD;         // aliased: proj in bf16 (SBLP shorts)
static constexpr size_t O_SDT  = O_PROJ + SBLP;                  // bf16: S*B*NCH*DI shorts
static constexpr size_t O_H    = O_SDT + (size_t)SS*BB*NCHF*DI;  // bf16 H: S*B*NCH*DI*NS shorts; aliased:
  // bf16 XBF [0,BLC) shorts, E1BF [BLC,2BLC), E2BF [2BLC,3BLC)  (dead before scan writes H)
  // bf16 GBF [0,BLD) shorts (written after scan, H dead)
static constexpr size_t O_M    = O_H + (size_t)SS*BB*NCHF*DI*NS;
static constexpr size_t O_S    = O_M + 2*(size_t)BB*2*LLn;
static constexpr size_t O_GF   = O_S + 2*(size_t)BB*LLn;   // aliased: bf16 in-proj weights
static constexpr size_t O_PART = O_GF + BLC;               // aliased: bf16 out_w
static constexpr size_t O_SIG  = O_PART + 2*(size_t)BB*32*CC;
static constexpr size_t WS_END = O_SIG + (size_t)BB*CC;

typedef __attribute__((ext_vector_type(8))) short short8v;   // 8 bf16 (4 VGPR)
typedef __attribute__((ext_vector_type(4))) float f32x4;     // MFMA acc

// ---- helpers ----
DEVI float bfu2f(unsigned short s){ union{unsigned u; float f;} c; c.u = ((unsigned)s)<<16; return c.f; }
DEVI unsigned short f2bfu(float f){ union{float f; unsigned u;} c; c.f=f;
  unsigned r = c.u + 0x7FFFu + ((c.u>>16)&1u); return (unsigned short)(r>>16); }
DEVI float4 bf4(uint2 v){ return make_float4(bfu2f((unsigned short)(v.x&0xFFFFu)), bfu2f((unsigned short)(v.x>>16)),
                                             bfu2f((unsigned short)(v.y&0xFFFFu)), bfu2f((unsigned short)(v.y>>16))); }
DEVI uint2 pk4(float4 v){ uint2 p;
  p.x = (unsigned)f2bfu(v.x) | ((unsigned)f2bfu(v.y)<<16);
  p.y = (unsigned)f2bfu(v.z) | ((unsigned)f2bfu(v.w)<<16); return p; }
DEVI bool bfmode(const void* ln1w){ return *(const unsigned*)ln1w == 0x3F803F80u; }
DEVI float2 ldin2(const void* p, int i, bool isbf){
  if(isbf){ unsigned v = *(const unsigned*)((const unsigned short*)p + i);
    return make_float2(bfu2f((unsigned short)(v & 0xFFFFu)), bfu2f((unsigned short)(v >> 16))); }
  const float* f = (const float*)p + i; return make_float2(f[0], f[1]);
}
DEVI float wsum(float v){
#pragma unroll
  for(int o=32;o;o>>=1) v += __shfl_xor(v,o,64);
  return v; }
DEVI float wmaxr(float v){
#pragma unroll
  for(int o=32;o;o>>=1) v = fmaxf(v, __shfl_xor(v,o,64));
  return v; }
DEVI float sigf(float x){ return 1.f/(1.f+__expf(-x)); }
// layernorm over 128 channels held as 2 values/lane across one 64-lane wave
DEVI float2 ln_wave(float2 x, const float* Wf, int ow, int ob, int lane){
  float mu = wsum(x.x + x.y) * (1.f/(float)CC);
  float dx = x.x - mu, dy = x.y - mu;
  float var = wsum(dx*dx + dy*dy) * (1.f/(float)CC);
  float rs = rsqrtf(var + 1e-5f);
  int c = 2*lane;
  return make_float2(dx*rs*Wf[ow+c] + Wf[ob+c], dy*rs*Wf[ow+c+1] + Wf[ob+c+1]);
}

struct Srcs { const void* p[22]; };

// K-1: zero the padded bf16 xproj weight block (4 streams x 64 rows x 256)
__global__ void k_xwpad(unsigned* __restrict__ xw32){
  int i = blockIdx.x*256 + threadIdx.x;     // 32768 uints = 65536 shorts
  xw32[i] = 0u;
}

// K0: convert all weight tensors to f32 workspace (+ bf16 copies of GEMM weights)
__global__ void k_wcvt(Srcs s, float* __restrict__ ws,
                       unsigned short* __restrict__ wip, unsigned short* __restrict__ wob,
                       unsigned short* __restrict__ xw){
  bool isbf = bfmode(s.p[0]);
  int idx = blockIdx.x*256 + threadIdx.x;
  if(idx >= NW_RAW) return;
  int t = 0;
  while(t < 21 && idx >= c_woff[t+1]) t++;
  int j = idx - c_woff[t];
  if(j >= c_wsz[t]) return;  // padding gap
  float v = isbf ? bfu2f(((const unsigned short*)s.p[t])[j]) : ((const float*)s.p[t])[j];
  ws[idx] = v;
  if(t==11)      wip[j]         = f2bfu(v);   // in_proj_w
  else if(t==12) wip[65536+j]   = f2bfu(v);   // in_proj1_w
  else if(t==13) wip[98304+j]   = f2bfu(v);   // in_proj2_w
  else if(t==21) wob[j]         = f2bfu(v);   // out_w
  else if(t==16){                             // xproj_w -> padded [s][64][256]
    int sid = j / 10240, rem = j % 10240;
    xw[((size_t)sid*64 + rem/256)*256 + (rem%256)] = f2bfu(v);
  }
}

// K1: fusion_resi = fusion + fusion_resi -> out1(f32); xf(bf16) = ln1(ln1(fr))
__global__ void k_fuse(const void* fus, const void* fres, const void* ln1raw,
                       float* __restrict__ ws, float* __restrict__ outf,
                       unsigned short* __restrict__ xbf){
  bool isbf = bfmode(ln1raw);
  int lane = threadIdx.x & 63, wv = threadIdx.x >> 6;
  int row = blockIdx.x*4 + wv;              // 16384 rows
  int base = row*CC;
  float2 a = ldin2(fus, base+2*lane, isbf);
  float2 b = ldin2(fres, base+2*lane, isbf);
  float2 fr = make_float2(a.x+b.x, a.y+b.y);
  *(float2*)(outf + BLC + base + 2*lane) = fr;      // output 1 = fusion_resi (f32)
  float2 y = ln_wave(fr, ws, OW_LN1W, OW_LN1B, lane);
  y = ln_wave(y, ws, OW_LN1W, OW_LN1B, lane);
  unsigned pk = (unsigned)f2bfu(y.x) | ((unsigned)f2bfu(y.y)<<16);
  *(unsigned*)&xbf[base + 2*lane] = pk;
}

// K2a: per-pixel channel mean/max of I1 (ten=0) and I2 (ten=1)
__global__ void k_meanmax(const void* I1, const void* I2, const void* ln1raw, float* __restrict__ ws){
  bool isbf = bfmode(ln1raw);
  int lane = threadIdx.x & 63, wv = threadIdx.x >> 6;
  int g = blockIdx.x*4 + wv;                // 32768 waves
  int ten = g & 1, row = g >> 1;
  const void* src = ten ? I2 : I1;
  float2 x = ldin2(src, row*CC + 2*lane, isbf);
  float sm = wsum(x.x + x.y) * (1.f/(float)CC);
  float mx = wmaxr(fmaxf(x.x, x.y));
  if(lane == 0){
    int b = row >> 12, l = row & 4095;
    float* mt = ws + O_M + (size_t)ten*(BB*2*LLn);
    mt[(size_t)b*2*LLn + l] = sm;
    mt[(size_t)b*2*LLn + LLn + l] = mx;
  }
}

// K2b: 5x5 conv (2ch->1) + sigmoid -> s1,s2
__global__ void k_spconv(float* __restrict__ ws){
  int idx = blockIdx.x*256 + threadIdx.x;   // 32768
  int ten = idx >> 14, b = (idx>>12)&3, l = idx & 4095;
  int h = l >> 6, w = l & 63;
  const float* mt = ws + O_M + (size_t)ten*(BB*2*LLn) + (size_t)b*2*LLn;
  float acc = 0.f;
  for(int ci=0; ci<2; ci++)
    for(int kh=0; kh<5; kh++){
      int hh = h + kh - 2; if((unsigned)hh >= 64u) continue;
      for(int kw=0; kw<5; kw++){
        int wn = w + kw - 2; if((unsigned)wn >= 64u) continue;
        acc += mt[(size_t)ci*LLn + hh*64 + wn] * ws[OW_SPW + ci*25 + kh*5 + kw];
      }
    }
  ws[O_S + (size_t)ten*(BB*LLn) + (size_t)b*LLn + l] = sigf(acc);
}

// K2c: e1(bf16) = ln2(ln2(I2*s2)), e2(bf16) = ln3(ln3(I1*s1))
__global__ void k_escale(const void* I1, const void* I2, const void* ln1raw,
                         float* __restrict__ ws, unsigned short* __restrict__ xbf){
  bool isbf = bfmode(ln1raw);
  int lane = threadIdx.x & 63, wv = threadIdx.x >> 6;
  int g = blockIdx.x*4 + wv;
  int ten = g & 1, row = g >> 1;            // ten0: e1 from I2; ten1: e2 from I1
  const void* src = ten ? I1 : I2;
  float sc = ws[O_S + (ten ? 0 : (size_t)BB*LLn) + row];
  float2 x = ldin2(src, row*CC + 2*lane, isbf);
  x.x *= sc; x.y *= sc;
  int ow = ten ? OW_LN3W : OW_LN2W, ob = ten ? OW_LN3B : OW_LN2B;
  float2 y = ln_wave(x, ws, ow, ob, lane);
  y = ln_wave(y, ws, ow, ob, lane);
  unsigned short* eb = xbf + (ten ? 2*BLC : BLC);
  unsigned pk = (unsigned)f2bfu(y.x) | ((unsigned)f2bfu(y.y)<<16);
  *(unsigned*)&eb[row*CC + 2*lane] = pk;
}

// K3: bf16 MFMA GEMM  out[m,n] = sum_k A[m,k]*W[n,k].
// 64x64 tile, 4 waves; 16x16x32 MFMA; XOR-swizzled LDS.
// mode 0: f32 out (n<N guard). mode 1: in-proj split u(bf16)/z(f32). mode 3: bf16 out.
__global__ __launch_bounds__(256) void k_gemm_bf(const unsigned short* __restrict__ Abf,
    const unsigned short* __restrict__ Wbf, float* __restrict__ out,
    int Kd, int N, int mode, unsigned short* __restrict__ ub16, float* __restrict__ z){
  __shared__ unsigned short As[64*64];
  __shared__ unsigned short Bs[64*64];
  const int tid = threadIdx.x, lane = tid & 63, w = tid >> 6;
  const int n0 = blockIdx.x*64, m0 = blockIdx.y*64;
  const int g = lane >> 4, rlo = lane & 15;
  f32x4 acc[4];
#pragma unroll
  for(int i=0;i<4;i++) acc[i] = (f32x4){0.f,0.f,0.f,0.f};
  const int nk = Kd >> 6;
  for(int kt=0; kt<nk; kt++){
#pragma unroll
    for(int it=0; it<2; it++){               // stage 64x64 bf16 A and B tiles
      int idx = it*256 + tid, r = idx>>3, c = idx&7;
      uint4 av = *(const uint4*)&Abf[(size_t)(m0+r)*Kd + kt*64 + c*8];
      uint4 bv = *(const uint4*)&Wbf[(size_t)(n0+r)*Kd + kt*64 + c*8];
      int sw = (c*16) ^ ((r&7)<<4);          // bank swizzle (G4)
      *(uint4*)((char*)As + r*128 + sw) = av;
      *(uint4*)((char*)Bs + r*128 + sw) = bv;
    }
    __syncthreads();
#pragma unroll
    for(int ks=0; ks<2; ks++){
      int kb = ks*64 + g*16;
      int brow = w*16 + rlo;
      short8v bf = *(short8v*)((char*)Bs + brow*128 + (kb ^ ((rlo&7)<<4)));
#pragma unroll
      for(int rt=0; rt<4; rt++){
        int arow = rt*16 + rlo;
        short8v af = *(short8v*)((char*)As + arow*128 + (kb ^ ((rlo&7)<<4)));
        acc[rt] = __builtin_amdgcn_mfma_f32_16x16x32_bf16(af, bf, acc[rt], 0, 0, 0);
      }
    }
    __syncthreads();
  }
#pragma unroll
  for(int rt=0; rt<4; rt++){
#pragma unroll
    for(int j=0; j<4; j++){
      int m = m0 + rt*16 + g*4 + j;          // D: row=(lane>>4)*4+reg, col=lane&15 [m89]
      int n = n0 + w*16 + rlo;
      float val = acc[rt][j];
      if(mode == 1){                          // in-proj split: u0 bf16 / z f32
        int b = m >> 12, l = m & (LLn-1);
        if(n < DI) ub16[((size_t)b*LLn + l)*DI + n] = f2bfu(val);
        else       z[((size_t)b*LLn + l)*DI + (n-DI)] = val;
      } else if(mode == 3){
        ub16[(size_t)m*N + n] = f2bfu(val);
      } else {
        if(n < N) out[(size_t)m*N + n] = val;
      }
    }
  }
}

// K4+K5 fused: causal dwconv(K=4)+SiLU computed during A-staging of the xproj GEMM.
// uc written to global (for scan) AND staged to LDS for MFMA. proj(bf16)[65536,40] = uc @ xw[s]^T.
__global__ __launch_bounds__(256) void k_cxgemm(const float* __restrict__ ws,
    const unsigned short* __restrict__ ubf, unsigned short* __restrict__ ucbf,
    const unsigned short* __restrict__ xwbf, unsigned short* __restrict__ pbf){
  __shared__ unsigned short As[64*64];
  __shared__ unsigned short Bs[64*64];
  __shared__ float cwl[DI*4 + DI];          // conv weights + bias for this stream (5 KB)
  const int tid = threadIdx.x, lane = tid & 63, w = tid >> 6;
  const int m0 = blockIdx.y*64;
  const int sb = m0 >> 12, s = sb >> 2, b = sb & 3, l0 = m0 & 4095;
  const int g = lane >> 4, rlo = lane & 15;
  const bool rev = (s == 1);
  const unsigned short* ub = ubf + (rev ? (size_t)b*LLn : (size_t)sb*LLn)*DI;
  const unsigned short* Wbf = xwbf + (size_t)s*(64*256);
#pragma unroll
  for(int i=0;i<5;i++){
    int idx = i*256 + tid;
    if(idx < DI*4)      cwl[idx] = ws[OW_CVW + (size_t)s*DI*4 + idx];
    else if(idx < DI*5) cwl[idx] = ws[OW_CVB + s*DI + (idx - DI*4)];
  }
  __syncthreads();
  f32x4 acc[4];
#pragma unroll
  for(int i=0;i<4;i++) acc[i] = (f32x4){0.f,0.f,0.f,0.f};
#pragma unroll
  for(int kt=0; kt<4; kt++){
#pragma unroll
    for(int it=0; it<2; it++){
      int idx = it*256 + tid, r = idx>>3, c = idx&7;
      int ch0 = kt*64 + c*8;
      int l = l0 + r;
      float4 ulo[4], uhi[4];
#pragma unroll
      for(int k=0;k<4;k++){
        int lm = l - 3 + k;
        if(lm < 0){ ulo[k]=make_float4(0,0,0,0); uhi[k]=make_float4(0,0,0,0); }
        else {
          uint4 uv = *(const uint4*)&ub[(size_t)(rev?(LLn-1-lm):lm)*DI + ch0];
          ulo[k] = bf4(make_uint2(uv.x,uv.y)); uhi[k] = bf4(make_uint2(uv.z,uv.w));
        }
      }
      float res[8];
#pragma unroll
      for(int j=0;j<4;j++){
        const float* cw = &cwl[(ch0+j)*4];
        float a = cwl[DI*4 + ch0 + j];
        float v0 = (&ulo[0].x)[j], v1 = (&ulo[1].x)[j], v2 = (&ulo[2].x)[j], v3 = (&ulo[3].x)[j];
        a += cw[0]*v0 + cw[1]*v1 + cw[2]*v2 + cw[3]*v3;
        res[j] = a * sigf(a);
      }
#pragma unroll
      for(int j=0;j<4;j++){
        const float* cw = &cwl[(ch0+4+j)*4];
        float a = cwl[DI*4 + ch0 + 4 + j];
        float v0 = (&uhi[0].x)[j], v1 = (&uhi[1].x)[j], v2 = (&uhi[2].x)[j], v3 = (&uhi[3].x)[j];
        a += cw[0]*v0 + cw[1]*v1 + cw[2]*v2 + cw[3]*v3;
        res[4+j] = a * sigf(a);
      }
      uint2 plo = pk4(make_float4(res[0],res[1],res[2],res[3]));
      uint2 phi = pk4(make_float4(res[4],res[5],res[6],res[7]));
      uint4 pk = make_uint4(plo.x, plo.y, phi.x, phi.y);
      *(uint4*)&ucbf[((size_t)sb*LLn + l)*DI + ch0] = pk;          // uc for the scan
      int sw = (c*16) ^ ((r&7)<<4);
      *(uint4*)((char*)As + r*128 + sw) = pk;
      uint4 bv = *(const uint4*)&Wbf[(size_t)r*256 + kt*64 + c*8];
      *(uint4*)((char*)Bs + r*128 + sw) = bv;
    }
    __syncthreads();
#pragma unroll
    for(int ks=0; ks<2; ks++){
      int kb = ks*64 + g*16;
      int brow = w*16 + rlo;
      short8v bf = *(short8v*)((char*)Bs + brow*128 + (kb ^ ((rlo&7)<<4)));
#pragma unroll
      for(int rt=0; rt<4; rt++){
        int arow = rt*16 + rlo;
        short8v af = *(short8v*)((char*)As + arow*128 + (kb ^ ((rlo&7)<<4)));
        acc[rt] = __builtin_amdgcn_mfma_f32_16x16x32_bf16(af, bf, acc[rt], 0, 0, 0);
      }
    }
    __syncthreads();
  }
#pragma unroll
  for(int rt=0; rt<4; rt++){
#pragma unroll
    for(int j=0; j<4; j++){
      int m = m0 + rt*16 + g*4 + j;
      int n = w*16 + rlo;
      if(n < PP) pbf[(size_t)m*PP + n] = f2bfu(acc[rt][j]);
    }
  }
}

// K6/K8: chunk-parallel selective scan (CT=64; proj/uc/H/Sdt bf16, f32 math, f32 LDS staging).
// PH3=false: local scan -> Hend,Sdt. PH3=true: re-run with h_in, emit y (bf16).
template<bool PH3>
__global__ __launch_bounds__(256) void k_scan(float* __restrict__ ws,
                                              const unsigned short* __restrict__ ucbf,
                                              const unsigned short* __restrict__ pbf){
  __shared__ float pl[CT*PP];               // 2560 floats = 10 KB
  int ch = blockIdx.x & (NCH-1), sb = blockIdx.x >> 6, s = sb >> 2;
  int d = threadIdx.x;
  size_t prow = ((size_t)sb*LLn + (size_t)ch*CT)*PP;
#pragma unroll
  for(int i=0;i<10;i++){ int idx = i*256 + threadIdx.x; pl[idx] = bfu2f(pbf[prow + idx]); }
  __syncthreads();
  unsigned short* ybf = (unsigned short*)(ws + O_U);   // y overwrites dead u (bf16)
  unsigned short* Hb  = (unsigned short*)(ws + O_H);   // bf16 chunk states
  unsigned short* Sdb = (unsigned short*)(ws + O_SDT); // bf16 chunk dt sums
  float4 dtw0 = *(const float4*)&ws[OW_DTW + ((size_t)s*DI + d)*RR];
  float4 dtw1 = *(const float4*)&ws[OW_DTW + ((size_t)s*DI + d)*RR + 4];
  float dtb = ws[OW_DTB + s*DI + d];
  float an2[NS]; bool fast = true;
#pragma unroll
  for(int n=0;n<NS;n++){
    float a = -__expf(ws[OW_ALOG + ((size_t)s*DI + d)*NS + n]);
    an2[n] = a * 1.44269504f;
    fast = fast && (fabsf(a + (float)(n+1)) < 1e-4f);
  }
  float4 h0,h1,h2,h3;
  size_t hb = (((size_t)sb*NCH + ch)*DI + d)*NS;        // short index
  if(PH3){
    uint4 ha = *(const uint4*)&Hb[hb];
    uint4 hc = *(const uint4*)&Hb[hb+8];
    h0 = bf4(make_uint2(ha.x,ha.y)); h1 = bf4(make_uint2(ha.z,ha.w));
    h2 = bf4(make_uint2(hc.x,hc.y)); h3 = bf4(make_uint2(hc.z,hc.w));
  } else {
    h0=h1=h2=h3=make_float4(0.f,0.f,0.f,0.f);
  }
  float dsk = PH3 ? ws[OW_DSK + s*DI + d] : 0.f;
  float sdt = 0.f;
  size_t ub = ((size_t)sb*LLn + (size_t)ch*CT)*DI + d;
  if(fast){
    for(int ll=0; ll<CT; ll++){
      const float* pr = &pl[ll*PP];
      float4 p0 = *(const float4*)pr, p1 = *(const float4*)(pr+4);
      float x = dtb + p0.x*dtw0.x + p0.y*dtw0.y + p0.z*dtw0.z + p0.w*dtw0.w
                    + p1.x*dtw1.x + p1.y*dtw1.y + p1.z*dtw1.z + p1.w*dtw1.w;
      float dt = (x > 15.f) ? x : __logf(1.f + __expf(x));
      float ut = bfu2f(ucbf[ub + (size_t)ll*DI]);
      float du = dt*ut;
      float e = __expf(-dt);
      float e2 = e*e, e4 = e2*e2;
      float4 da = make_float4(e, e2, e2*e, e4);   // e^1..e^4
      float4 B0 = *(const float4*)(pr+8),  B1 = *(const float4*)(pr+12),
             B2 = *(const float4*)(pr+16), B3 = *(const float4*)(pr+20);
      if(PH3){
        float4 C0 = *(const float4*)(pr+24), C1 = *(const float4*)(pr+28),
               C2 = *(const float4*)(pr+32), C3 = *(const float4*)(pr+36);
        float y;
        h0.x = fmaf(h0.x, da.x, du*B0.x); y  = h0.x*C0.x;
        h0.y = fmaf(h0.y, da.y, du*B0.y); y = fmaf(h0.y, C0.y, y);
        h0.z = fmaf(h0.z, da.z, du*B0.z); y = fmaf(h0.z, C0.z, y);
        h0.w = fmaf(h0.w, da.w, du*B0.w); y = fmaf(h0.w, C0.w, y);
        da.x *= e4; da.y *= e4; da.z *= e4; da.w *= e4;       // e^5..e^8
        h1.x = fmaf(h1.x, da.x, du*B1.x); y = fmaf(h1.x, C1.x, y);
        h1.y = fmaf(h1.y, da.y, du*B1.y); y = fmaf(h1.y, C1.y, y);
        h1.z = fmaf(h1.z, da.z, du*B1.z); y = fmaf(h1.z, C1.z, y);
        h1.w = fmaf(h1.w, da.w, du*B1.w); y = fmaf(h1.w, C1.w, y);
        da.x *= e4; da.y *= e4; da.z *= e4; da.w *= e4;       // e^9..e^12
        h2.x = fmaf(h2.x, da.x, du*B2.x); y = fmaf(h2.x, C2.x, y);
        h2.y = fmaf(h2.y, da.y, du*B2.y); y = fmaf(h2.y, C2.y, y);
        h2.z = fmaf(h2.z, da.z, du*B2.z); y = fmaf(h2.z, C2.z, y);
        h2.w = fmaf(h2.w, da.w, du*B2.w); y = fmaf(h2.w, C2.w, y);
        da.x *= e4; da.y *= e4; da.z *= e4; da.w *= e4;       // e^13..e^16
        h3.x = fmaf(h3.x, da.x, du*B3.x); y = fmaf(h3.x, C3.x, y);
        h3.y = fmaf(h3.y, da.y, du*B3.y); y = fmaf(h3.y, C3.y, y);
        h3.z = fmaf(h3.z, da.z, du*B3.z); y = fmaf(h3.z, C3.z, y);
        h3.w = fmaf(h3.w, da.w, du*B3.w); y = fmaf(h3.w, C3.w, y);
        ybf[ub + (size_t)ll*DI] = f2bfu(y + ut*dsk);
      } else {
        h0.x = fmaf(h0.x, da.x, du*B0.x); h0.y = fmaf(h0.y, da.y, du*B0.y);
        h0.z = fmaf(h0.z, da.z, du*B0.z); h0.w = fmaf(h0.w, da.w, du*B0.w);
        da.x *= e4; da.y *= e4; da.z *= e4; da.w *= e4;
        h1.x = fmaf(h1.x, da.x, du*B1.x); h1.y = fmaf(h1.y, da.y, du*B1.y);
        h1.z = fmaf(h1.z, da.z, du*B1.z); h1.w = fmaf(h1.w, da.w, du*B1.w);
        da.x *= e4; da.y *= e4; da.z *= e4; da.w *= e4;
        h2.x = fmaf(h2.x, da.x, du*B2.x); h2.y = fmaf(h2.y, da.y, du*B2.y);
        h2.z = fmaf(h2.z, da.z, du*B2.z); h2.w = fmaf(h2.w, da.w, du*B2.w);
        da.x *= e4; da.y *= e4; da.z *= e4; da.w *= e4;
        h3.x = fmaf(h3.x, da.x, du*B3.x); h3.y = fmaf(h3.y, da.y, du*B3.y);
        h3.z = fmaf(h3.z, da.z, du*B3.z); h3.w = fmaf(h3.w, da.w, du*B3.w);
        sdt += dt;
      }
    }
  } else {
    float h[NS];
    h[0]=h0.x;h[1]=h0.y;h[2]=h0.z;h[3]=h0.w; h[4]=h1.x;h[5]=h1.y;h[6]=h1.z;h[7]=h1.w;
    h[8]=h2.x;h[9]=h2.y;h[10]=h2.z;h[11]=h2.w; h[12]=h3.x;h[13]=h3.y;h[14]=h3.z;h[15]=h3.w;
    for(int ll=0; ll<CT; ll++){
      const float* pr = &pl[ll*PP];
      float x = dtb;
      x += pr[0]*dtw0.x + pr[1]*dtw0.y + pr[2]*dtw0.z + pr[3]*dtw0.w;
      x += pr[4]*dtw1.x + pr[5]*dtw1.y + pr[6]*dtw1.z + pr[7]*dtw1.w;
      float dt = (x > 15.f) ? x : __logf(1.f + __expf(x));
      float ut = bfu2f(ucbf[ub + (size_t)ll*DI]);
      float du = dt*ut;
      if(PH3){
        float y = 0.f;
#pragma unroll
        for(int n=0;n<NS;n++){ float da = exp2f(an2[n]*dt); h[n] = h[n]*da + du*pr[RR+n]; y += h[n]*pr[RR+NS+n]; }
        ybf[ub + (size_t)ll*DI] = f2bfu(y + ut*dsk);
      } else {
#pragma unroll
        for(int n=0;n<NS;n++){ float da = exp2f(an2[n]*dt); h[n] = h[n]*da + du*pr[RR+n]; }
        sdt += dt;
      }
    }
    h0=make_float4(h[0],h[1],h[2],h[3]); h1=make_float4(h[4],h[5],h[6],h[7]);
    h2=make_float4(h[8],h[9],h[10],h[11]); h3=make_float4(h[12],h[13],h[14],h[15]);
  }
  if(!PH3){
    uint2 a = pk4(h0), b2 = pk4(h1), c = pk4(h2), dd = pk4(h3);
    *(uint4*)&Hb[hb]   = make_uint4(a.x,a.y,b2.x,b2.y);
    *(uint4*)&Hb[hb+8] = make_uint4(c.x,c.y,dd.x,dd.y);
    Sdb[((size_t)sb*NCH + ch)*DI + d] = f2bfu(sdt);
  }
}

// K7: combine chunk boundary states (bf16 H/Sdt, coalesced): Hend -> Hin, in place
__global__ void k_scan2(float* __restrict__ ws){
  int t = blockIdx.x*256 + threadIdx.x;     // 65536 = S*B*DI*NS
  int n = t & (NS-1), d = (t>>4) & (DI-1), sb = t >> 12, s = sb >> 2;
  float an2 = -__expf(ws[OW_ALOG + ((size_t)s*DI + d)*NS + n]) * 1.44269504f;
  float hin = 0.f;
  unsigned short* Hb  = (unsigned short*)(ws + O_H);
  const unsigned short* Sdb = (const unsigned short*)(ws + O_SDT);
  for(int c=0;c<NCH;c++){
    size_t hi = (((size_t)sb*NCH + c)*DI + d)*NS + n;
    float he = bfu2f(Hb[hi]);
    float sd = bfu2f(Sdb[((size_t)sb*NCH + c)*DI + d]);
    Hb[hi] = f2bfu(hin);
    hin = he + exp2f(an2*sd)*hin;
  }
}

// K9: combine 4 streams (stream1 re-reversed, bf16 y), gate with silu(z) -> gbf (bf16)
__global__ void k_gate(float* __restrict__ ws, unsigned short* __restrict__ gbf){
  int t = blockIdx.x*256 + threadIdx.x;     // BLD/4
  int d4 = t & 63, l = (t>>6)&4095, b = t>>18;
  int d0 = d4*4;
  const unsigned short* ybf = (const unsigned short*)(ws + O_U);
  size_t i0 = ((size_t)(0*BB+b)*LLn + l)*DI + d0;
  size_t i1 = ((size_t)(1*BB+b)*LLn + (LLn-1-l))*DI + d0;
  size_t i2 = ((size_t)(2*BB+b)*LLn + l)*DI + d0;
  size_t i3 = ((size_t)(3*BB+b)*LLn + l)*DI + d0;
  float4 a = bf4(*(const uint2*)&ybf[i0]);
  float4 bb4 = bf4(*(const uint2*)&ybf[i1]);
  float4 c = bf4(*(const uint2*)&ybf[i2]);
  float4 dd = bf4(*(const uint2*)&ybf[i3]);
  size_t zi = ((size_t)b*LLn + l)*DI + d0;
  float4 zv = *(const float4*)&ws[O_Z + zi];
  float4 g;
  g.x = (a.x+bb4.x+c.x+dd.x) * (zv.x*sigf(zv.x));
  g.y = (a.y+bb4.y+c.y+dd.y) * (zv.y*sigf(zv.y));
  g.z = (a.z+bb4.z+c.z+dd.z) * (zv.z*sigf(zv.z));
  g.w = (a.w+bb4.w+c.w+dd.w) * (zv.w*sigf(zv.w));
  *(uint2*)&gbf[zi] = pk4(g);
}

// K10: partial spatial mean/max of gf per (b, 128-row segment)
__global__ void k_redmm(float* __restrict__ ws){
  int b = blockIdx.x >> 5, seg = blockIdx.x & 31, c = threadIdx.x; // 128 threads
  const float* gf = ws + O_GF;
  float sm = 0.f, mx = -3e38f;
  size_t base = ((size_t)b*LLn + (size_t)seg*128)*CC + c;
  for(int i=0;i<128;i++){ float v = gf[base + (size_t)i*CC]; sm += v; mx = fmaxf(mx, v); }
  ws[O_PART + ((size_t)b*32 + seg)*CC + c] = sm;
  ws[O_PART + (size_t)BB*32*CC + ((size_t)b*32 + seg)*CC + c] = mx;
}

// K11: channel attention MLP -> sig[b,c]
__global__ void k_catt(float* __restrict__ ws){
  __shared__ float vm[CC], vx[CC], hm[32], hx[32];
  int b = blockIdx.x, c = threadIdx.x;      // 128 threads
  float sm = 0.f, mx = -3e38f;
  for(int seg=0;seg<32;seg++){
    sm += ws[O_PART + ((size_t)b*32+seg)*CC + c];
    mx = fmaxf(mx, ws[O_PART + (size_t)BB*32*CC + ((size_t)b*32+seg)*CC + c]);
  }
  vm[c] = sm * (1.f/(float)LLn); vx[c] = mx;
  __syncthreads();
  if(c < 32){
    float am = 0.f, ax = 0.f;
    for(int k=0;k<CC;k++){ float w1 = ws[OW_CAW1 + c*CC + k]; am += vm[k]*w1; ax += vx[k]*w1; }
    hm[c] = fmaxf(am, 0.f); hx[c] = fmaxf(ax, 0.f);
  }
  __syncthreads();
  float om = 0.f, ox = 0.f;
  for(int k=0;k<32;k++){ float w2 = ws[OW_CAW2 + c*32 + k]; om += hm[k]*w2; ox += hx[k]*w2; }
  ws[O_SIG + (size_t)b*CC + c] = sigf(om + ox);
}

// K12: f4 = gf^2*sig; out0 = dwconv3x3(f4) + dw_b + f4  (f32)
__global__ void k_final(float* __restrict__ ws, float* __restrict__ outf){
  int t = blockIdx.x*256 + threadIdx.x;     // B*L*C/4 = 524288
  int c4 = t & 31, l = (t>>5)&4095, b = t>>17;
  int h = l>>6, w = l&63;
  const float* gf = ws + O_GF;
  float4 sg = *(const float4*)&ws[O_SIG + (size_t)b*CC + c4*4];
  size_t rb = ((size_t)b*LLn)*CC;
  float4 gc = *(const float4*)&gf[rb + (size_t)l*CC + c4*4];
  float4 fc = make_float4(gc.x*gc.x*sg.x, gc.y*gc.y*sg.y, gc.z*gc.z*sg.z, gc.w*gc.w*sg.w);
  float4 acc = *(const float4*)&ws[OW_DWB + c4*4];
  float wv[4][9];
#pragma unroll
  for(int j=0;j<4;j++)
#pragma unroll
    for(int q=0;q<9;q++) wv[j][q] = ws[OW_DWW + (c4*4+j)*9 + q];
#pragma unroll
  for(int kh=0;kh<3;kh++){
    int hh = h + kh - 1; if((unsigned)hh >= 64u) continue;
#pragma unroll
    for(int kw=0;kw<3;kw++){
      int wn = w + kw - 1; if((unsigned)wn >= 64u) continue;
      float4 g = *(const float4*)&gf[rb + (size_t)(hh*64+wn)*CC + c4*4];
      int q = kh*3+kw;
      acc.x += wv[0][q]*g.x*g.x*sg.x;
      acc.y += wv[1][q]*g.y*g.y*sg.y;
      acc.z += wv[2][q]*g.z*g.z*sg.z;
      acc.w += wv[3][q]*g.w*g.w*sg.w;
    }
  }
  float4 o = make_float4(acc.x+fc.x, acc.y+fc.y, acc.z+fc.z, acc.w+fc.w);
  size_t ob = ((size_t)b*LLn + l)*CC + c4*4;
  *(float4*)&outf[ob] = o;                  // output 0 (f32)
}

extern "C" void kernel_launch(void* const* d_in, const int* in_sizes, int n_in,
                              void* d_out, int out_size, void* d_ws, size_t ws_size,
                              hipStream_t stream){
  (void)in_sizes; (void)n_in; (void)out_size;
  if(ws_size < WS_END*sizeof(float)) return;
  float* ws = (float*)d_ws;
  float* outf = (float*)d_out;              // f32 outputs (reference returns float32)
  const void* I1 = d_in[0]; const void* FRES = d_in[1];
  const void* I2 = d_in[2]; const void* FUS  = d_in[3];
  const void* LN1RAW = d_in[4];

  // bf16 aliases over dead-at-the-time f32 regions
  unsigned short* xbf   = (unsigned short*)(ws + O_H);    // xf [0,BLC), e1 [BLC,2BLC), e2 [2BLC,3BLC)
  unsigned short* gbf   = xbf;                            // gated, after scan (H dead)
  unsigned short* wipbf = (unsigned short*)(ws + O_GF);   // ipw | ip1w | ip2w (bf16)
  unsigned short* wobf  = (unsigned short*)(ws + O_PART); // out_w (bf16)
  unsigned short* xwbf  = (unsigned short*)(ws + O_XF);   // padded xproj weights [4][64][256] bf16
  unsigned short* ucbf  = (unsigned short*)(ws + O_UC);   // uc bf16 [S*B*L][256]
  unsigned short* ubf   = (unsigned short*)(ws + O_U);    // u bf16 [S*B*L][256]; later y bf16
  unsigned short* pbf   = (unsigned short*)(ws + O_PROJ); // proj bf16 [S*B*L][40]

  Srcs sr;
  for(int i=0;i<22;i++) sr.p[i] = d_in[4+i];
  k_xwpad<<<128, 256, 0, stream>>>((unsigned*)xwbf);
  k_wcvt<<<(NW_RAW+255)/256, 256, 0, stream>>>(sr, ws, wipbf, wobf, xwbf);
  k_fuse<<<4096, 256, 0, stream>>>(FUS, FRES, LN1RAW, ws, outf, xbf);
  k_meanmax<<<8192, 256, 0, stream>>>(I1, I2, LN1RAW, ws);
  k_spconv<<<128, 256, 0, stream>>>(ws);
  k_escale<<<8192, 256, 0, stream>>>(I1, I2, LN1RAW, ws, xbf);
  // MFMA GEMMs: in-proj (split u0 bf16 / z f32), e1->u2 bf16, e2->u3 bf16
  k_gemm_bf<<<dim3(8,256), 256, 0, stream>>>(xbf,         wipbf,       nullptr,      128, 512, 1, ubf,        ws+O_Z);
  k_gemm_bf<<<dim3(4,256), 256, 0, stream>>>(xbf+BLC,     wipbf+65536, nullptr,      128, 256, 3, ubf+2*BLD,  nullptr);
  k_gemm_bf<<<dim3(4,256), 256, 0, stream>>>(xbf+2*BLC,   wipbf+98304, nullptr,      128, 256, 3, ubf+3*BLD,  nullptr);
  // fused conv+SiLU+xproj GEMM: writes uc (bf16) and proj (bf16)
  k_cxgemm<<<dim3(1,1024), 256, 0, stream>>>(ws, ubf, ucbf, xwbf, pbf);
  k_scan<false><<<SS*BB*NCH, 256, 0, stream>>>(ws, ucbf, pbf);
  k_scan2<<<256, 256, 0, stream>>>(ws);
  k_scan<true><<<SS*BB*NCH, 256, 0, stream>>>(ws, ucbf, pbf);
  k_gate<<<4096, 256, 0, stream>>>(ws, gbf);
  // out-proj: gf = g @ out_w.T  (reads gbf at O_H, writes O_GF over dead wipbf)
  k_gemm_bf<<<dim3(2,256), 256, 0, stream>>>(gbf, wobf, ws+O_GF, 256, 128, 0, nullptr, nullptr);
  k_redmm<<<128, 128, 0, stream>>>(ws);
  k_catt<<<4, 128, 0, stream>>>(ws);
  k_final<<<2048, 256, 0, stream>>>(ws, outf);
}